// Round 1
// baseline (237.570 us; speedup 1.0000x reference)
//
#include <hip/hip_runtime.h>
#include <hip/hip_bf16.h>

typedef __attribute__((ext_vector_type(8))) short short8;
typedef __attribute__((ext_vector_type(4))) float f32x4;
typedef __attribute__((ext_vector_type(4))) short short4v;

// Problem constants
#define BB 8
#define NN 1024
#define DD 512
#define OO 512
#define HH 8
#define HD 64
#define MM (BB * NN)  // 8192

#define QSC 0.18033688f       // 0.125 * log2(e): folded into Q at projection
#define KSHIFT -11.54156032f  // -8*log2(e): softmax shift, fused into key bias
#define KMASKED -30000.0f     // masked key: exp2 underflows to exactly 0

// Async global->LDS, 16B/lane (m97 recipe). LDS dest = wave-uniform base +
// lane*16 -> unpadded tiles.
__device__ __forceinline__ void gload_lds16(const void* g, void* l) {
  __builtin_amdgcn_global_load_lds(
      (const __attribute__((address_space(1))) void*)g,
      (__attribute__((address_space(3))) void*)l, 16, 0, 0);
}

__device__ __forceinline__ uint2 cvt4(float4 v) {
  union { uint2 u; __hip_bfloat16 h[4]; } t;
  t.h[0] = __float2bfloat16(v.x);
  t.h[1] = __float2bfloat16(v.y);
  t.h[2] = __float2bfloat16(v.z);
  t.h[3] = __float2bfloat16(v.w);
  return t.u;
}

// ---------------------------------------------------------------------------
// Input conversion. PROVEN: float inputs fp32, mask int32 {0,1}, output fp32.
// ---------------------------------------------------------------------------
#define SEG_N 10
struct ConvArgs {
  const float* src[SEG_N];
  __hip_bfloat16* dst[SEG_N];
  int n4[SEG_N];
};

__global__ void convert_kernel(ConvArgs a) {
  const int t = blockIdx.y;
  const int n4 = a.n4[t];
  const float4* fs = (const float4*)a.src[t];
  uint2* d = (uint2*)a.dst[t];
  for (int i = blockIdx.x * blockDim.x + threadIdx.x; i < n4;
       i += gridDim.x * blockDim.x)
    d[i] = cvt4(fs[i]);
}

// ---------------------------------------------------------------------------
// 128x128-tile GEMM (global_load_lds both sides), qkv epilogue.
// 1D grid of 768, XCD-banded swizzle: XCD k owns rows [1024k, 1024k+1024)
// (x-band 1 MB bf16, L2-resident -> x fetched once per XCD, not 4x).
// Q (pre-scaled QSC), K -> [B,H,N,64]; V -> [B,H,64,N] transposed via LDS.
// ---------------------------------------------------------------------------
__global__ __launch_bounds__(256) void gemm_qkv(
    const __hip_bfloat16* __restrict__ A0, const __hip_bfloat16* __restrict__ B0,
    const __hip_bfloat16* __restrict__ bias0,
    __hip_bfloat16* __restrict__ out0, __hip_bfloat16* __restrict__ out1,
    __hip_bfloat16* __restrict__ out2, int Kd) {
  __shared__ __align__(16) __hip_bfloat16 smem[8192];  // As 128x32 | Bs 128x32
  __hip_bfloat16* As = smem;
  __hip_bfloat16* Bs = smem + 4096;

  const int tid  = threadIdx.x;
  const int wave = tid >> 6;
  const int lane = tid & 63;
  const int fl   = lane & 15;
  const int fk   = (lane >> 4) * 8;
  const int wm   = (wave & 1) * 64;
  const int wn   = (wave >> 1) * 64;
  // XCD-banded swizzle (768 blocks = 64 rowparts x 12 colparts)
  const int bid     = blockIdx.x;
  const int rowpart = 8 * (bid & 7) + ((bid >> 3) & 7);
  const int colpart = bid >> 6;
  const int m0 = rowpart * 128;
  const int n0 = colpart * 128;
  const int glr  = lane >> 2;
  const int glc  = (lane & 3) * 8;

  f32x4 acc[4][4];
#pragma unroll
  for (int i = 0; i < 4; ++i)
#pragma unroll
    for (int j = 0; j < 4; ++j) acc[i][j] = (f32x4){0.f, 0.f, 0.f, 0.f};

  char* lb = (char*)smem;
  for (int k0 = 0; k0 < Kd; k0 += 32) {
    __syncthreads();
    gload_lds16(A0 + (size_t)(m0 + wave * 16 + glr) * Kd + k0 + glc,
                lb + wave * 1024 + lane * 16);
    gload_lds16(A0 + (size_t)(m0 + 64 + wave * 16 + glr) * Kd + k0 + glc,
                lb + (wave + 4) * 1024 + lane * 16);
    gload_lds16(B0 + (size_t)(n0 + wave * 16 + glr) * Kd + k0 + glc,
                lb + 8192 + wave * 1024 + lane * 16);
    gload_lds16(B0 + (size_t)(n0 + 64 + wave * 16 + glr) * Kd + k0 + glc,
                lb + 8192 + (wave + 4) * 1024 + lane * 16);
    __syncthreads();

    short8 af[4], bfr[4];
#pragma unroll
    for (int i = 0; i < 4; ++i)
      af[i] = *(const short8*)&As[(wm + i * 16 + fl) * 32 + fk];
#pragma unroll
    for (int j = 0; j < 4; ++j)
      bfr[j] = *(const short8*)&Bs[(wn + j * 16 + fl) * 32 + fk];
#pragma unroll
    for (int i = 0; i < 4; ++i)
#pragma unroll
      for (int j = 0; j < 4; ++j)
        acc[i][j] = __builtin_amdgcn_mfma_f32_16x16x32_bf16(af[i], bfr[j],
                                                            acc[i][j], 0, 0, 0);
  }

  const int rb = (lane >> 4) * 4;
  const int part = n0 >> 9;  // block-uniform
  if (part < 2) {
    __hip_bfloat16* dst = (part == 0) ? out0 : out1;
    const float scf = (part == 0) ? QSC : 1.0f;
#pragma unroll
    for (int j = 0; j < 4; ++j) {
      const int colb  = n0 + wn + j * 16;
      const int o     = colb & 511;
      const int headq = o >> 6;
      const int d     = (o & 63) + fl;
      const float bi  = __bfloat162float(bias0[colb + fl]);
#pragma unroll
      for (int i = 0; i < 4; ++i) {
#pragma unroll
        for (int r = 0; r < 4; ++r) {
          const int row = m0 + wm + i * 16 + rb + r;
          const int bb  = row >> 10;
          const int nn  = row & 1023;
          dst[((size_t)((bb << 3) + headq) * NN + nn) * HD + d] =
              __float2bfloat16((acc[i][j][r] + bi) * scf);
        }
      }
    }
  } else {
    // V: transpose 64x16 pieces through LDS, coalesced dwordx4 stores
    __syncthreads();  // uniform; smem free for scratch
    __hip_bfloat16* tsc = smem + wave * 1120;  // 16 x 70 per wave
    const int bb  = (m0 + wm) >> 10;
    const int nnb = (m0 + wm) & 1023;
    const int dl  = lane >> 2;
    const int cc  = (lane & 3) * 16;
#pragma unroll
    for (int j = 0; j < 4; ++j) {
      const int colb  = n0 + wn + j * 16;
      const int o     = colb & 511;
      const int headq = o >> 6;
      const int dbase = o & 63;
      const float bi  = __bfloat162float(bias0[colb + fl]);
#pragma unroll
      for (int i = 0; i < 4; ++i) {
#pragma unroll
        for (int r = 0; r < 4; ++r) {
          const int rr = i * 16 + rb + r;
          tsc[fl * 70 + rr] = __float2bfloat16(acc[i][j][r] + bi);
        }
      }
      uint4 r0 = *(const uint4*)&tsc[dl * 70 + cc];
      uint4 r1 = *(const uint4*)&tsc[dl * 70 + cc + 8];
      __hip_bfloat16* vdst =
          out2 + ((size_t)((bb << 3) + headq) * HD + dbase + dl) * NN + nnb;
      *(uint4*)&vdst[cc] = r0;
      *(uint4*)&vdst[cc + 8] = r1;
    }
  }
}

// ---------------------------------------------------------------------------
// 64x128-tile GEMM (global_load_lds), FFN GEMMs. Was 64x64 (4 MFMA/wave-step);
// now 8 MFMA/wave-step (m92/m103: bigger tile = better staging amortization).
// 1D grid of 512, XCD-banded: XCD k owns rows [1024k, 1024k+1024) -> ffn1's
// t-band is read back by the SAME XCD's ffn2 blocks (1 MB, L2-hit).
// MODE 1: relu(acc + bias0) * rowmask -> out0 bf16
// MODE 2: 0.5*(accA+accB + bias1 + (rowmask ? bias0 : 0)) -> outf fp32
// ---------------------------------------------------------------------------
template <int MODE>
__global__ __launch_bounds__(256) void gemm_ffn(
    const __hip_bfloat16* __restrict__ A0, const __hip_bfloat16* __restrict__ B0,
    const __hip_bfloat16* __restrict__ A1, const __hip_bfloat16* __restrict__ B1,
    const __hip_bfloat16* __restrict__ bias0, const __hip_bfloat16* __restrict__ bias1,
    const int* __restrict__ mask,
    __hip_bfloat16* __restrict__ out0, float* __restrict__ outf,
    int N, int Kd) {
  __shared__ __align__(16) __hip_bfloat16 smem[6144];  // As 64x32 | Bs 128x32
  __hip_bfloat16* As = smem;
  __hip_bfloat16* Bs = smem + 2048;

  const int tid  = threadIdx.x;
  const int wave = tid >> 6;
  const int lane = tid & 63;
  const int fl   = lane & 15;
  const int fk   = (lane >> 4) * 8;
  const int wm   = (wave & 1) * 32;
  const int wn   = (wave >> 1) * 64;
  // XCD-banded swizzle (512 blocks = 128 rowparts x 4 colparts)
  const int bid     = blockIdx.x;
  const int rowpart = 16 * (bid & 7) + ((bid >> 3) & 15);
  const int colpart = bid >> 7;
  const int m0 = rowpart * 64;
  const int n0 = colpart * 128;
  const int glr  = lane >> 2;
  const int glc  = (lane & 3) * 8;

  f32x4 acc[2][4];
#pragma unroll
  for (int i = 0; i < 2; ++i)
#pragma unroll
    for (int j = 0; j < 4; ++j) acc[i][j] = (f32x4){0.f, 0.f, 0.f, 0.f};

  char* lb = (char*)smem;
  const int npairs = (MODE == 2) ? 2 : 1;
  for (int p = 0; p < npairs; ++p) {
    const __hip_bfloat16* Ap = (p == 0) ? A0 : A1;
    const __hip_bfloat16* Bp = (p == 0) ? B0 : B1;
    for (int k0 = 0; k0 < Kd; k0 += 32) {
      __syncthreads();
      gload_lds16(Ap + (size_t)(m0 + wave * 16 + glr) * Kd + k0 + glc,
                  lb + wave * 1024 + lane * 16);
      gload_lds16(Bp + (size_t)(n0 + wave * 16 + glr) * Kd + k0 + glc,
                  lb + 4096 + wave * 1024 + lane * 16);
      gload_lds16(Bp + (size_t)(n0 + 64 + wave * 16 + glr) * Kd + k0 + glc,
                  lb + 8192 + wave * 1024 + lane * 16);
      __syncthreads();

      short8 af[2], bfr[4];
#pragma unroll
      for (int i = 0; i < 2; ++i)
        af[i] = *(const short8*)&As[(wm + i * 16 + fl) * 32 + fk];
#pragma unroll
      for (int j = 0; j < 4; ++j)
        bfr[j] = *(const short8*)&Bs[(wn + j * 16 + fl) * 32 + fk];
#pragma unroll
      for (int i = 0; i < 2; ++i)
#pragma unroll
        for (int j = 0; j < 4; ++j)
          acc[i][j] = __builtin_amdgcn_mfma_f32_16x16x32_bf16(af[i], bfr[j],
                                                              acc[i][j], 0, 0, 0);
    }
  }

  const int rb = (lane >> 4) * 4;
  if (MODE == 1) {
#pragma unroll
    for (int j = 0; j < 4; ++j) {
      const int col  = n0 + wn + j * 16 + fl;
      const float bi = __bfloat162float(bias0[col]);
#pragma unroll
      for (int i = 0; i < 2; ++i) {
#pragma unroll
        for (int r = 0; r < 4; ++r) {
          const int row = m0 + wm + i * 16 + rb + r;
          float v = fmaxf(acc[i][j][r] + bi, 0.f);
          if (mask[row] == 0) v = 0.f;
          out0[(size_t)row * N + col] = __float2bfloat16(v);
        }
      }
    }
  } else {
#pragma unroll
    for (int j = 0; j < 4; ++j) {
      const int col   = n0 + wn + j * 16 + fl;
      const float b2v = __bfloat162float(bias0[col]);
      const float brv = __bfloat162float(bias1[col]);
#pragma unroll
      for (int i = 0; i < 2; ++i) {
#pragma unroll
        for (int r = 0; r < 4; ++r) {
          const int row = m0 + wm + i * 16 + rb + r;
          const float v = acc[i][j][r] + brv + (mask[row] != 0 ? b2v : 0.f);
          outf[(size_t)row * N + col] = 0.5f * v;
        }
      }
    }
  }
}

// ---------------------------------------------------------------------------
// Attention: 128-row Q tile, 512 threads (8 waves x 16 q-rows), KVBLK=128.
// vs previous rev: barriers halved (16 vs 32 per block), T14 async-stage
// (next K/V tile's global loads issued right after the staging barrier ->
// a full tile of compute hides their latency), T5 setprio around MFMA
// clusters, Ps aliased onto Qs (Q is register-hoisted before the loop) to
// keep LDS at 58.4 KB -> 2 blocks/CU.
// S^T trick (A=K, B=Q): packed b64 P-writes, float4 mask-bias, scalar lsum.
// Q pre-scaled by 0.125*log2(e); Msf fuses mask + shift (log2 domain).
// blockIdx = qblk*64 + bh (XCD-local K/V).
// ---------------------------------------------------------------------------
__global__ __launch_bounds__(512) void attn_kernel(
    const __hip_bfloat16* __restrict__ Qb, const __hip_bfloat16* __restrict__ Kb,
    const __hip_bfloat16* __restrict__ Vt, const __hip_bfloat16* __restrict__ slw,
    const int* __restrict__ mask, __hip_bfloat16* __restrict__ hb) {
  __shared__ __align__(16) __hip_bfloat16 QPs[128 * 72];  // Q pre-loop, then P
  __shared__ __align__(16) __hip_bfloat16 Ks[128 * 72];
  __shared__ __align__(16) __hip_bfloat16 Vs[64 * 136];
  __shared__ float Msf[NN];

  const int tid  = threadIdx.x;
  const int wave = tid >> 6;
  const int lane = tid & 63;
  const int fl   = lane & 15;
  const int quad = lane >> 4;
  const int fk   = quad * 8;
  const int rb   = quad * 4;
  const int bh   = blockIdx.x & 63;
  const int qblk = blockIdx.x >> 6;
  const int b    = bh >> 3;
  const int head = bh & 7;
  const int q0   = qblk * 128;

  const float slwL2 = __bfloat162float(slw[head]) * 1.44269504f;

  {
    const int srow = tid >> 2;
    const int sc   = (tid & 3) * 16;
    const __hip_bfloat16* qg = Qb + ((size_t)bh * NN + q0) * HD;
    uint4 v0 = *(const uint4*)(qg + srow * HD + sc);
    uint4 v1 = *(const uint4*)(qg + srow * HD + sc + 8);
    *(uint4*)&QPs[srow * 72 + sc] = v0;
    *(uint4*)&QPs[srow * 72 + sc + 8] = v1;
#pragma unroll
    for (int k = 0; k < 2; ++k) {
      const int idx = tid * 2 + k;
      Msf[idx] = (mask[b * NN + idx] != 0) ? KSHIFT : KMASKED;
    }
  }
  __syncthreads();
  // Q register-hoist: QPs is dead after this -> reused as P buffer.
  // (reads/writes of QPs rows are wave-local afterwards, so no extra sync)
  const short8 qa0 = *(const short8*)&QPs[(wave * 16 + fl) * 72 + fk];
  const short8 qa1 = *(const short8*)&QPs[(wave * 16 + fl) * 72 + fk + 32];

  // staging geometry: K tile 128x64 (2 uint4/thread), V^T tile 64x128 (2)
  const int srK = tid >> 2;          // 0..127
  const int scK = (tid & 3) * 16;    // 0,16,32,48
  const int srV = tid >> 3;          // 0..63
  const int scV = (tid & 7) * 16;    // 0..112

  const __hip_bfloat16* kgb = Kb + (size_t)bh * NN * HD;
  const __hip_bfloat16* vgb = Vt + (size_t)bh * HD * NN;

  // T14 prefetch registers: tile kb=0
  uint4 kr0 = *(const uint4*)(kgb + (size_t)srK * HD + scK);
  uint4 kr1 = *(const uint4*)(kgb + (size_t)srK * HD + scK + 8);
  uint4 vr0 = *(const uint4*)(vgb + (size_t)srV * NN + scV);
  uint4 vr1 = *(const uint4*)(vgb + (size_t)srV * NN + scV + 8);

  float lsum = 0.f;
  f32x4 Oacc[4];
#pragma unroll
  for (int t = 0; t < 4; ++t) Oacc[t] = (f32x4){0.f, 0.f, 0.f, 0.f};

  for (int kb = 0; kb < NN / 128; ++kb) {
    __syncthreads();  // all waves done reading previous K/V tile
    *(uint4*)&Ks[srK * 72 + scK] = kr0;
    *(uint4*)&Ks[srK * 72 + scK + 8] = kr1;
    *(uint4*)&Vs[srV * 136 + scV] = vr0;
    *(uint4*)&Vs[srV * 136 + scV + 8] = vr1;
    __syncthreads();  // staging visible

    // issue next tile's global loads NOW; consumed at next iteration's
    // staging -> full tile of compute hides global (L2) latency.
    if (kb + 1 < NN / 128) {
      const int nk = (kb + 1) * 128;
      kr0 = *(const uint4*)(kgb + (size_t)(nk + srK) * HD + scK);
      kr1 = *(const uint4*)(kgb + (size_t)(nk + srK) * HD + scK + 8);
      vr0 = *(const uint4*)(vgb + (size_t)srV * NN + nk + scV);
      vr1 = *(const uint4*)(vgb + (size_t)srV * NN + nk + scV + 8);
    }

    f32x4 sfr[8];
    __builtin_amdgcn_s_setprio(1);
#pragma unroll
    for (int j = 0; j < 8; ++j) {
      const short8 kf0 = *(const short8*)&Ks[(j * 16 + fl) * 72 + fk];
      const short8 kf1 = *(const short8*)&Ks[(j * 16 + fl) * 72 + fk + 32];
      f32x4 z = (f32x4){0.f, 0.f, 0.f, 0.f};
      z = __builtin_amdgcn_mfma_f32_16x16x32_bf16(kf0, qa0, z, 0, 0, 0);
      z = __builtin_amdgcn_mfma_f32_16x16x32_bf16(kf1, qa1, z, 0, 0, 0);
      sfr[j] = z;
    }
    __builtin_amdgcn_s_setprio(0);

    // diagonal self-loop bias: key_local == qrow_local within kb==qblk.
    // all indices compile-time (rule #20: no runtime ext_vector indexing).
    if (kb == qblk && (fl >> 2) == quad) {
#pragma unroll
      for (int j = 0; j < 8; ++j)
        if (wave == j) {
#pragma unroll
          for (int e = 0; e < 4; ++e)
            if ((fl & 3) == e) sfr[j][e] += slwL2;
        }
    }

    const int kbase = kb * 128;
#pragma unroll
    for (int c = 0; c < 2; ++c) {
#pragma unroll
      for (int jj = 0; jj < 4; ++jj) {
        const f32x4 s4  = sfr[c * 4 + jj];
        const f32x4 mb4 = *(const f32x4*)&Msf[kbase + c * 64 + jj * 16 + quad * 4];
        union { short4v s; __hip_bfloat16 h[4]; } pu;
        float ps = 0.f;
#pragma unroll
        for (int e = 0; e < 4; ++e) {
          const float pv = exp2f(s4[e] + mb4[e]);
          ps += pv;
          pu.h[e] = __float2bfloat16(pv);
        }
        lsum += ps;
        *(short4v*)&QPs[(wave * 16 + fl) * 72 + jj * 16 + quad * 4] = pu.s;
      }

      const short8 pa0 = *(const short8*)&QPs[(wave * 16 + fl) * 72 + fk];
      const short8 pa1 = *(const short8*)&QPs[(wave * 16 + fl) * 72 + fk + 32];
      __builtin_amdgcn_s_setprio(1);
#pragma unroll
      for (int t = 0; t < 4; ++t) {
        const short8 vf0 = *(const short8*)&Vs[(t * 16 + fl) * 136 + c * 64 + fk];
        const short8 vf1 = *(const short8*)&Vs[(t * 16 + fl) * 136 + c * 64 + fk + 32];
        Oacc[t] = __builtin_amdgcn_mfma_f32_16x16x32_bf16(pa0, vf0, Oacc[t], 0, 0, 0);
        Oacc[t] = __builtin_amdgcn_mfma_f32_16x16x32_bf16(pa1, vf1, Oacc[t], 0, 0, 0);
      }
      __builtin_amdgcn_s_setprio(0);
    }
  }

  float l = lsum;
  l += __shfl_xor(l, 16, 64);
  l += __shfl_xor(l, 32, 64);
  const int qrow_me = q0 + wave * 16 + fl;
  const float qm = (mask[b * NN + qrow_me] != 0) ? 1.f : 0.f;
  const float sf = qm / fmaxf(l, 1e-30f);

  float scl[4];
#pragma unroll
  for (int r = 0; r < 4; ++r) scl[r] = __shfl(sf, rb + r, 64);

#pragma unroll
  for (int t = 0; t < 4; ++t) {
    const int d = t * 16 + fl;
#pragma unroll
    for (int r = 0; r < 4; ++r) {
      const int qrow_g = q0 + wave * 16 + rb + r;
      hb[(size_t)(b * NN + qrow_g) * OO + head * HD + d] =
          __float2bfloat16(Oacc[t][r] * scl[r]);
    }
  }
}

extern "C" void kernel_launch(void* const* d_in, const int* in_sizes, int n_in,
                              void* d_out, int out_size, void* d_ws, size_t ws_size,
                              hipStream_t stream) {
  const float* x_raw    = (const float*)d_in[0];
  const int* mask       = (const int*)d_in[2];
  const float* slw_raw  = (const float*)d_in[3];
  const float* qkvw_raw = (const float*)d_in[4];
  const float* qkvb_raw = (const float*)d_in[5];
  const float* w1_raw   = (const float*)d_in[6];
  const float* b1_raw   = (const float*)d_in[7];
  const float* w2_raw   = (const float*)d_in[8];
  const float* b2_raw   = (const float*)d_in[9];
  const float* wr_raw   = (const float*)d_in[10];
  const float* br_raw   = (const float*)d_in[11];
  float* outf           = (float*)d_out;

  __hip_bfloat16* p = (__hip_bfloat16*)d_ws;
  __hip_bfloat16* xc    = p; p += (size_t)MM * DD;
  __hip_bfloat16* qkvwc = p; p += 3 * OO * DD;
  __hip_bfloat16* w1c   = p; p += OO * OO;
  __hip_bfloat16* w2c   = p; p += OO * OO;
  __hip_bfloat16* wrc   = p; p += OO * DD;
  __hip_bfloat16* qkvbc = p; p += 3 * OO;
  __hip_bfloat16* b1c   = p; p += OO;
  __hip_bfloat16* b2c   = p; p += OO;
  __hip_bfloat16* brc   = p; p += OO;
  __hip_bfloat16* slwc  = p; p += 64;
  const size_t ebuf = (size_t)BB * HH * NN * HD;
  __hip_bfloat16* Qb = p; p += ebuf;
  __hip_bfloat16* Kb = p; p += ebuf;
  __hip_bfloat16* Vb = p; p += ebuf;   // V^T layout [B,H,64,N]
  __hip_bfloat16* hb = (__hip_bfloat16*)d_out;  // attn out scratch in d_out;
                                                // fully consumed by ffn1
  __hip_bfloat16* tb = Kb;  // ffn hidden aliases Kb (dead after attention)

  if (ws_size < (size_t)((char*)p - (char*)d_ws)) return;

  ConvArgs ca;
  ca.src[0] = x_raw;    ca.dst[0] = xc;    ca.n4[0] = MM * DD / 4;
  ca.src[1] = qkvw_raw; ca.dst[1] = qkvwc; ca.n4[1] = 3 * OO * DD / 4;
  ca.src[2] = w1_raw;   ca.dst[2] = w1c;   ca.n4[2] = OO * OO / 4;
  ca.src[3] = w2_raw;   ca.dst[3] = w2c;   ca.n4[3] = OO * OO / 4;
  ca.src[4] = wr_raw;   ca.dst[4] = wrc;   ca.n4[4] = OO * DD / 4;
  ca.src[5] = qkvb_raw; ca.dst[5] = qkvbc; ca.n4[5] = 3 * OO / 4;
  ca.src[6] = b1_raw;   ca.dst[6] = b1c;   ca.n4[6] = OO / 4;
  ca.src[7] = b2_raw;   ca.dst[7] = b2c;   ca.n4[7] = OO / 4;
  ca.src[8] = br_raw;   ca.dst[8] = brc;   ca.n4[8] = OO / 4;
  ca.src[9] = slw_raw;  ca.dst[9] = slwc;  ca.n4[9] = HH / 4;
  convert_kernel<<<dim3(128, SEG_N), 256, 0, stream>>>(ca);

  // 1) qkv projection (XCD-banded); Q pre-scaled, K row-major, V transposed
  gemm_qkv<<<768, 256, 0, stream>>>(xc, qkvwc, qkvbc, Qb, Kb, Vb, DD);
  // 2) attention (+ query fmask) -> hb (scratch inside d_out)
  attn_kernel<<<BB * HH * (NN / 128), 512, 0, stream>>>(Qb, Kb, Vb, slwc, mask, hb);
  // 3) ffn layer 1 (XCD-banded): relu(h@w1^T + b1), masked rows zeroed
  gemm_ffn<1><<<512, 256, 0, stream>>>(
      hb, w1c, nullptr, nullptr, b1c, nullptr, mask, tb, nullptr, OO, OO);
  // 4) ffn layer 2 + residual (XCD-banded, t-band L2-resident) -> fp32 out
  gemm_ffn<2><<<512, 256, 0, stream>>>(
      tb, w2c, xc, wrc, b2c, brc, mask, nullptr, outf, OO, DD);
}

// Round 2
// 222.258 us; speedup vs baseline: 1.0689x; 1.0689x over previous
//
#include <hip/hip_runtime.h>
#include <hip/hip_bf16.h>

typedef __attribute__((ext_vector_type(8))) short short8;
typedef __attribute__((ext_vector_type(4))) float f32x4;
typedef __attribute__((ext_vector_type(4))) short short4v;

// Problem constants
#define BB 8
#define NN 1024
#define DD 512
#define OO 512
#define HH 8
#define HD 64
#define MM (BB * NN)  // 8192

#define QSC 0.18033688f       // 0.125 * log2(e): folded into Q at projection
#define KSHIFT -11.54156032f  // -8*log2(e): softmax shift, fused into key bias
#define KMASKED -30000.0f     // masked key: exp2 underflows to exactly 0

// Async global->LDS, 16B/lane (m97 recipe). LDS dest = wave-uniform base +
// lane*16 -> unpadded tiles.
__device__ __forceinline__ void gload_lds16(const void* g, void* l) {
  __builtin_amdgcn_global_load_lds(
      (const __attribute__((address_space(1))) void*)g,
      (__attribute__((address_space(3))) void*)l, 16, 0, 0);
}

__device__ __forceinline__ uint2 cvt4(float4 v) {
  union { uint2 u; __hip_bfloat16 h[4]; } t;
  t.h[0] = __float2bfloat16(v.x);
  t.h[1] = __float2bfloat16(v.y);
  t.h[2] = __float2bfloat16(v.z);
  t.h[3] = __float2bfloat16(v.w);
  return t.u;
}

// ---------------------------------------------------------------------------
// Input conversion. PROVEN: float inputs fp32, mask int32 {0,1}, output fp32.
// ---------------------------------------------------------------------------
#define SEG_N 10
struct ConvArgs {
  const float* src[SEG_N];
  __hip_bfloat16* dst[SEG_N];
  int n4[SEG_N];
};

__global__ void convert_kernel(ConvArgs a) {
  const int t = blockIdx.y;
  const int n4 = a.n4[t];
  const float4* fs = (const float4*)a.src[t];
  uint2* d = (uint2*)a.dst[t];
  for (int i = blockIdx.x * blockDim.x + threadIdx.x; i < n4;
       i += gridDim.x * blockDim.x)
    d[i] = cvt4(fs[i]);
}

// ---------------------------------------------------------------------------
// 128x128-tile GEMM (global_load_lds both sides), qkv epilogue.
// 1D grid of 768, XCD-banded swizzle: XCD k owns rows [1024k, 1024k+1024)
// (x-band 1 MB bf16, L2-resident -> x fetched once per XCD, not 4x).
// Q (pre-scaled QSC), K -> [B,H,N,64]; V -> [B,H,64,N] transposed via LDS.
// ---------------------------------------------------------------------------
__global__ __launch_bounds__(256) void gemm_qkv(
    const __hip_bfloat16* __restrict__ A0, const __hip_bfloat16* __restrict__ B0,
    const __hip_bfloat16* __restrict__ bias0,
    __hip_bfloat16* __restrict__ out0, __hip_bfloat16* __restrict__ out1,
    __hip_bfloat16* __restrict__ out2, int Kd) {
  __shared__ __align__(16) __hip_bfloat16 smem[8192];  // As 128x32 | Bs 128x32
  __hip_bfloat16* As = smem;
  __hip_bfloat16* Bs = smem + 4096;

  const int tid  = threadIdx.x;
  const int wave = tid >> 6;
  const int lane = tid & 63;
  const int fl   = lane & 15;
  const int fk   = (lane >> 4) * 8;
  const int wm   = (wave & 1) * 64;
  const int wn   = (wave >> 1) * 64;
  // XCD-banded swizzle (768 blocks = 64 rowparts x 12 colparts)
  const int bid     = blockIdx.x;
  const int rowpart = 8 * (bid & 7) + ((bid >> 3) & 7);
  const int colpart = bid >> 6;
  const int m0 = rowpart * 128;
  const int n0 = colpart * 128;
  const int glr  = lane >> 2;
  const int glc  = (lane & 3) * 8;

  f32x4 acc[4][4];
#pragma unroll
  for (int i = 0; i < 4; ++i)
#pragma unroll
    for (int j = 0; j < 4; ++j) acc[i][j] = (f32x4){0.f, 0.f, 0.f, 0.f};

  char* lb = (char*)smem;
  for (int k0 = 0; k0 < Kd; k0 += 32) {
    __syncthreads();
    gload_lds16(A0 + (size_t)(m0 + wave * 16 + glr) * Kd + k0 + glc,
                lb + wave * 1024 + lane * 16);
    gload_lds16(A0 + (size_t)(m0 + 64 + wave * 16 + glr) * Kd + k0 + glc,
                lb + (wave + 4) * 1024 + lane * 16);
    gload_lds16(B0 + (size_t)(n0 + wave * 16 + glr) * Kd + k0 + glc,
                lb + 8192 + wave * 1024 + lane * 16);
    gload_lds16(B0 + (size_t)(n0 + 64 + wave * 16 + glr) * Kd + k0 + glc,
                lb + 8192 + (wave + 4) * 1024 + lane * 16);
    __syncthreads();

    short8 af[4], bfr[4];
#pragma unroll
    for (int i = 0; i < 4; ++i)
      af[i] = *(const short8*)&As[(wm + i * 16 + fl) * 32 + fk];
#pragma unroll
    for (int j = 0; j < 4; ++j)
      bfr[j] = *(const short8*)&Bs[(wn + j * 16 + fl) * 32 + fk];
#pragma unroll
    for (int i = 0; i < 4; ++i)
#pragma unroll
      for (int j = 0; j < 4; ++j)
        acc[i][j] = __builtin_amdgcn_mfma_f32_16x16x32_bf16(af[i], bfr[j],
                                                            acc[i][j], 0, 0, 0);
  }

  const int rb = (lane >> 4) * 4;
  const int part = n0 >> 9;  // block-uniform
  if (part < 2) {
    __hip_bfloat16* dst = (part == 0) ? out0 : out1;
    const float scf = (part == 0) ? QSC : 1.0f;
#pragma unroll
    for (int j = 0; j < 4; ++j) {
      const int colb  = n0 + wn + j * 16;
      const int o     = colb & 511;
      const int headq = o >> 6;
      const int d     = (o & 63) + fl;
      const float bi  = __bfloat162float(bias0[colb + fl]);
#pragma unroll
      for (int i = 0; i < 4; ++i) {
#pragma unroll
        for (int r = 0; r < 4; ++r) {
          const int row = m0 + wm + i * 16 + rb + r;
          const int bb  = row >> 10;
          const int nn  = row & 1023;
          dst[((size_t)((bb << 3) + headq) * NN + nn) * HD + d] =
              __float2bfloat16((acc[i][j][r] + bi) * scf);
        }
      }
    }
  } else {
    // V: transpose 64x16 pieces through LDS, coalesced dwordx4 stores
    __syncthreads();  // uniform; smem free for scratch
    __hip_bfloat16* tsc = smem + wave * 1120;  // 16 x 70 per wave
    const int bb  = (m0 + wm) >> 10;
    const int nnb = (m0 + wm) & 1023;
    const int dl  = lane >> 2;
    const int cc  = (lane & 3) * 16;
#pragma unroll
    for (int j = 0; j < 4; ++j) {
      const int colb  = n0 + wn + j * 16;
      const int o     = colb & 511;
      const int headq = o >> 6;
      const int dbase = o & 63;
      const float bi  = __bfloat162float(bias0[colb + fl]);
#pragma unroll
      for (int i = 0; i < 4; ++i) {
#pragma unroll
        for (int r = 0; r < 4; ++r) {
          const int rr = i * 16 + rb + r;
          tsc[fl * 70 + rr] = __float2bfloat16(acc[i][j][r] + bi);
        }
      }
      uint4 r0 = *(const uint4*)&tsc[dl * 70 + cc];
      uint4 r1 = *(const uint4*)&tsc[dl * 70 + cc + 8];
      __hip_bfloat16* vdst =
          out2 + ((size_t)((bb << 3) + headq) * HD + dbase + dl) * NN + nnb;
      *(uint4*)&vdst[cc] = r0;
      *(uint4*)&vdst[cc + 8] = r1;
    }
  }
}

// ---------------------------------------------------------------------------
// 64x128-tile GEMM (global_load_lds), FFN GEMMs. 8 MFMA/wave-step.
// 1D grid of 512, XCD-banded: XCD k owns rows [1024k, 1024k+1024) -> ffn1's
// t-band is read back by the SAME XCD's ffn2 blocks (1 MB, L2-hit).
// MODE 1: relu(acc + bias0) * rowmask -> out0 bf16
// MODE 2: 0.5*(accA+accB + bias1 + (rowmask ? bias0 : 0)) -> outf fp32
// ---------------------------------------------------------------------------
template <int MODE>
__global__ __launch_bounds__(256) void gemm_ffn(
    const __hip_bfloat16* __restrict__ A0, const __hip_bfloat16* __restrict__ B0,
    const __hip_bfloat16* __restrict__ A1, const __hip_bfloat16* __restrict__ B1,
    const __hip_bfloat16* __restrict__ bias0, const __hip_bfloat16* __restrict__ bias1,
    const int* __restrict__ mask,
    __hip_bfloat16* __restrict__ out0, float* __restrict__ outf,
    int N, int Kd) {
  __shared__ __align__(16) __hip_bfloat16 smem[6144];  // As 64x32 | Bs 128x32
  __hip_bfloat16* As = smem;
  __hip_bfloat16* Bs = smem + 2048;

  const int tid  = threadIdx.x;
  const int wave = tid >> 6;
  const int lane = tid & 63;
  const int fl   = lane & 15;
  const int fk   = (lane >> 4) * 8;
  const int wm   = (wave & 1) * 32;
  const int wn   = (wave >> 1) * 64;
  // XCD-banded swizzle (512 blocks = 128 rowparts x 4 colparts)
  const int bid     = blockIdx.x;
  const int rowpart = 16 * (bid & 7) + ((bid >> 3) & 15);
  const int colpart = bid >> 7;
  const int m0 = rowpart * 64;
  const int n0 = colpart * 128;
  const int glr  = lane >> 2;
  const int glc  = (lane & 3) * 8;

  f32x4 acc[2][4];
#pragma unroll
  for (int i = 0; i < 2; ++i)
#pragma unroll
    for (int j = 0; j < 4; ++j) acc[i][j] = (f32x4){0.f, 0.f, 0.f, 0.f};

  char* lb = (char*)smem;
  const int npairs = (MODE == 2) ? 2 : 1;
  for (int p = 0; p < npairs; ++p) {
    const __hip_bfloat16* Ap = (p == 0) ? A0 : A1;
    const __hip_bfloat16* Bp = (p == 0) ? B0 : B1;
    for (int k0 = 0; k0 < Kd; k0 += 32) {
      __syncthreads();
      gload_lds16(Ap + (size_t)(m0 + wave * 16 + glr) * Kd + k0 + glc,
                  lb + wave * 1024 + lane * 16);
      gload_lds16(Bp + (size_t)(n0 + wave * 16 + glr) * Kd + k0 + glc,
                  lb + 4096 + wave * 1024 + lane * 16);
      gload_lds16(Bp + (size_t)(n0 + 64 + wave * 16 + glr) * Kd + k0 + glc,
                  lb + 8192 + wave * 1024 + lane * 16);
      __syncthreads();

      short8 af[2], bfr[4];
#pragma unroll
      for (int i = 0; i < 2; ++i)
        af[i] = *(const short8*)&As[(wm + i * 16 + fl) * 32 + fk];
#pragma unroll
      for (int j = 0; j < 4; ++j)
        bfr[j] = *(const short8*)&Bs[(wn + j * 16 + fl) * 32 + fk];
#pragma unroll
      for (int i = 0; i < 2; ++i)
#pragma unroll
        for (int j = 0; j < 4; ++j)
          acc[i][j] = __builtin_amdgcn_mfma_f32_16x16x32_bf16(af[i], bfr[j],
                                                              acc[i][j], 0, 0, 0);
    }
  }

  const int rb = (lane >> 4) * 4;
  if (MODE == 1) {
#pragma unroll
    for (int j = 0; j < 4; ++j) {
      const int col  = n0 + wn + j * 16 + fl;
      const float bi = __bfloat162float(bias0[col]);
#pragma unroll
      for (int i = 0; i < 2; ++i) {
#pragma unroll
        for (int r = 0; r < 4; ++r) {
          const int row = m0 + wm + i * 16 + rb + r;
          float v = fmaxf(acc[i][j][r] + bi, 0.f);
          if (mask[row] == 0) v = 0.f;
          out0[(size_t)row * N + col] = __float2bfloat16(v);
        }
      }
    }
  } else {
#pragma unroll
    for (int j = 0; j < 4; ++j) {
      const int col   = n0 + wn + j * 16 + fl;
      const float b2v = __bfloat162float(bias0[col]);
      const float brv = __bfloat162float(bias1[col]);
#pragma unroll
      for (int i = 0; i < 2; ++i) {
#pragma unroll
        for (int r = 0; r < 4; ++r) {
          const int row = m0 + wm + i * 16 + rb + r;
          const float v = acc[i][j][r] + brv + (mask[row] != 0 ? b2v : 0.f);
          outf[(size_t)row * N + col] = 0.5f * v;
        }
      }
    }
  }
}

// ---------------------------------------------------------------------------
// Attention: 128-row Q tile, 512 threads (8 waves x 16 q-rows), KVBLK=64
// (round-0 geometry: sfr[4], small live set -> no spills). Deltas vs r0:
//  - Ps aliased onto Qs (Q register-hoisted pre-loop): LDS 59392 -> 40960
//    -> 3-4 blocks/CU instead of 2 (barrier bubbles filled cross-block).
//  - T14 prefetch: next K/V tile in 2 uint4 regs (8 VGPRs), issued right
//    after the staging barrier -> full tile of compute hides load latency.
//  - T5 setprio around both MFMA clusters.
// S^T trick (A=K, B=Q): packed b64 P-writes, float4 mask-bias, scalar lsum.
// Q pre-scaled by 0.125*log2(e); Msf fuses mask + shift (log2 domain).
// blockIdx = qblk*64 + bh (XCD-local K/V).
// ---------------------------------------------------------------------------
__global__ __launch_bounds__(512) void attn_kernel(
    const __hip_bfloat16* __restrict__ Qb, const __hip_bfloat16* __restrict__ Kb,
    const __hip_bfloat16* __restrict__ Vt, const __hip_bfloat16* __restrict__ slw,
    const int* __restrict__ mask, __hip_bfloat16* __restrict__ hb) {
  __shared__ __align__(16) __hip_bfloat16 QPs[128 * 72];  // Q pre-loop, then P
  __shared__ __align__(16) __hip_bfloat16 Ks[64 * 72];
  __shared__ __align__(16) __hip_bfloat16 Vs[64 * 72];
  __shared__ float Msf[NN];

  const int tid  = threadIdx.x;
  const int wave = tid >> 6;
  const int lane = tid & 63;
  const int fl   = lane & 15;
  const int quad = lane >> 4;
  const int fk   = quad * 8;
  const int rb   = quad * 4;
  const int bh   = blockIdx.x & 63;
  const int qblk = blockIdx.x >> 6;
  const int b    = bh >> 3;
  const int head = bh & 7;
  const int q0   = qblk * 128;

  const float slwL2 = __bfloat162float(slw[head]) * 1.44269504f;

  {
    const int srow = tid >> 2;
    const int sc   = (tid & 3) * 16;
    const __hip_bfloat16* qg = Qb + ((size_t)bh * NN + q0) * HD;
    uint4 v0 = *(const uint4*)(qg + srow * HD + sc);
    uint4 v1 = *(const uint4*)(qg + srow * HD + sc + 8);
    *(uint4*)&QPs[srow * 72 + sc] = v0;
    *(uint4*)&QPs[srow * 72 + sc + 8] = v1;
#pragma unroll
    for (int k = 0; k < 2; ++k) {
      const int idx = tid * 2 + k;
      Msf[idx] = (mask[b * NN + idx] != 0) ? KSHIFT : KMASKED;
    }
  }
  __syncthreads();
  // Q register-hoist: QPs is dead after this -> reused as P buffer.
  // (P rows are wave-local afterwards, so no extra sync needed)
  const short8 qa0 = *(const short8*)&QPs[(wave * 16 + fl) * 72 + fk];
  const short8 qa1 = *(const short8*)&QPs[(wave * 16 + fl) * 72 + fk + 32];

  // staging geometry: K tile 64x64, V^T tile 64x64 -> 1 uint4/thread each
  const int srow2 = tid >> 3;        // 0..63
  const int sc2   = (tid & 7) * 8;   // 0..56

  const __hip_bfloat16* kgb = Kb + (size_t)bh * NN * HD;
  const __hip_bfloat16* vgb = Vt + (size_t)bh * HD * NN;

  // T14 prefetch registers: tile kb=0 (8 VGPRs total)
  uint4 kr = *(const uint4*)(kgb + (size_t)srow2 * HD + sc2);
  uint4 vr = *(const uint4*)(vgb + (size_t)srow2 * NN + sc2);

  float lsum = 0.f;
  f32x4 Oacc[4];
#pragma unroll
  for (int t = 0; t < 4; ++t) Oacc[t] = (f32x4){0.f, 0.f, 0.f, 0.f};

  const int kbdiag = 2 * qblk + (wave >> 2);

  for (int kb = 0; kb < NN / 64; ++kb) {
    const int kbase = kb * 64;
    __syncthreads();  // all waves done reading previous K/V tile
    *(uint4*)&Ks[srow2 * 72 + sc2] = kr;
    *(uint4*)&Vs[srow2 * 72 + sc2] = vr;
    __syncthreads();  // staging visible

    // issue next tile's global loads NOW; consumed at next iteration's
    // staging -> a full tile of compute hides the (L2) load latency.
    if (kb + 1 < NN / 64) {
      const int nk = kbase + 64;
      kr = *(const uint4*)(kgb + (size_t)(nk + srow2) * HD + sc2);
      vr = *(const uint4*)(vgb + (size_t)srow2 * NN + nk + sc2);
    }

    f32x4 sfr[4];
    __builtin_amdgcn_s_setprio(1);
#pragma unroll
    for (int j = 0; j < 4; ++j) {
      const short8 kf0 = *(const short8*)&Ks[(j * 16 + fl) * 72 + fk];
      const short8 kf1 = *(const short8*)&Ks[(j * 16 + fl) * 72 + fk + 32];
      f32x4 z = (f32x4){0.f, 0.f, 0.f, 0.f};
      z = __builtin_amdgcn_mfma_f32_16x16x32_bf16(kf0, qa0, z, 0, 0, 0);
      z = __builtin_amdgcn_mfma_f32_16x16x32_bf16(kf1, qa1, z, 0, 0, 0);
      sfr[j] = z;
    }
    __builtin_amdgcn_s_setprio(0);

    if (kb == kbdiag) {
      if ((fl >> 2) == quad) sfr[wave & 3][fl & 3] += slwL2;
    }

#pragma unroll
    for (int j = 0; j < 4; ++j) {
      const f32x4 mb4 = *(const f32x4*)&Msf[kbase + j * 16 + quad * 4];
      union { short4v s; __hip_bfloat16 h[4]; } pu;
      float ps = 0.f;
#pragma unroll
      for (int e = 0; e < 4; ++e) {
        const float pv = exp2f(sfr[j][e] + mb4[e]);
        ps += pv;
        pu.h[e] = __float2bfloat16(pv);
      }
      lsum += ps;
      *(short4v*)&QPs[(wave * 16 + fl) * 72 + j * 16 + quad * 4] = pu.s;
    }

    const short8 pa0 = *(const short8*)&QPs[(wave * 16 + fl) * 72 + fk];
    const short8 pa1 = *(const short8*)&QPs[(wave * 16 + fl) * 72 + fk + 32];
    __builtin_amdgcn_s_setprio(1);
#pragma unroll
    for (int t = 0; t < 4; ++t) {
      const short8 vf0 = *(const short8*)&Vs[(t * 16 + fl) * 72 + fk];
      const short8 vf1 = *(const short8*)&Vs[(t * 16 + fl) * 72 + fk + 32];
      Oacc[t] = __builtin_amdgcn_mfma_f32_16x16x32_bf16(pa0, vf0, Oacc[t], 0, 0, 0);
      Oacc[t] = __builtin_amdgcn_mfma_f32_16x16x32_bf16(pa1, vf1, Oacc[t], 0, 0, 0);
    }
    __builtin_amdgcn_s_setprio(0);
  }

  float l = lsum;
  l += __shfl_xor(l, 16, 64);
  l += __shfl_xor(l, 32, 64);
  const int qrow_me = q0 + wave * 16 + fl;
  const float qm = (mask[b * NN + qrow_me] != 0) ? 1.f : 0.f;
  const float sf = qm / fmaxf(l, 1e-30f);

  float scl[4];
#pragma unroll
  for (int r = 0; r < 4; ++r) scl[r] = __shfl(sf, rb + r, 64);

#pragma unroll
  for (int t = 0; t < 4; ++t) {
    const int d = t * 16 + fl;
#pragma unroll
    for (int r = 0; r < 4; ++r) {
      const int qrow_g = q0 + wave * 16 + rb + r;
      hb[(size_t)(b * NN + qrow_g) * OO + head * HD + d] =
          __float2bfloat16(Oacc[t][r] * scl[r]);
    }
  }
}

extern "C" void kernel_launch(void* const* d_in, const int* in_sizes, int n_in,
                              void* d_out, int out_size, void* d_ws, size_t ws_size,
                              hipStream_t stream) {
  const float* x_raw    = (const float*)d_in[0];
  const int* mask       = (const int*)d_in[2];
  const float* slw_raw  = (const float*)d_in[3];
  const float* qkvw_raw = (const float*)d_in[4];
  const float* qkvb_raw = (const float*)d_in[5];
  const float* w1_raw   = (const float*)d_in[6];
  const float* b1_raw   = (const float*)d_in[7];
  const float* w2_raw   = (const float*)d_in[8];
  const float* b2_raw   = (const float*)d_in[9];
  const float* wr_raw   = (const float*)d_in[10];
  const float* br_raw   = (const float*)d_in[11];
  float* outf           = (float*)d_out;

  __hip_bfloat16* p = (__hip_bfloat16*)d_ws;
  __hip_bfloat16* xc    = p; p += (size_t)MM * DD;
  __hip_bfloat16* qkvwc = p; p += 3 * OO * DD;
  __hip_bfloat16* w1c   = p; p += OO * OO;
  __hip_bfloat16* w2c   = p; p += OO * OO;
  __hip_bfloat16* wrc   = p; p += OO * DD;
  __hip_bfloat16* qkvbc = p; p += 3 * OO;
  __hip_bfloat16* b1c   = p; p += OO;
  __hip_bfloat16* b2c   = p; p += OO;
  __hip_bfloat16* brc   = p; p += OO;
  __hip_bfloat16* slwc  = p; p += 64;
  const size_t ebuf = (size_t)BB * HH * NN * HD;
  __hip_bfloat16* Qb = p; p += ebuf;
  __hip_bfloat16* Kb = p; p += ebuf;
  __hip_bfloat16* Vb = p; p += ebuf;   // V^T layout [B,H,64,N]
  __hip_bfloat16* hb = (__hip_bfloat16*)d_out;  // attn out scratch in d_out;
                                                // fully consumed by ffn1
  __hip_bfloat16* tb = Kb;  // ffn hidden aliases Kb (dead after attention)

  if (ws_size < (size_t)((char*)p - (char*)d_ws)) return;

  ConvArgs ca;
  ca.src[0] = x_raw;    ca.dst[0] = xc;    ca.n4[0] = MM * DD / 4;
  ca.src[1] = qkvw_raw; ca.dst[1] = qkvwc; ca.n4[1] = 3 * OO * DD / 4;
  ca.src[2] = w1_raw;   ca.dst[2] = w1c;   ca.n4[2] = OO * OO / 4;
  ca.src[3] = w2_raw;   ca.dst[3] = w2c;   ca.n4[3] = OO * OO / 4;
  ca.src[4] = wr_raw;   ca.dst[4] = wrc;   ca.n4[4] = OO * DD / 4;
  ca.src[5] = qkvb_raw; ca.dst[5] = qkvbc; ca.n4[5] = 3 * OO / 4;
  ca.src[6] = b1_raw;   ca.dst[6] = b1c;   ca.n4[6] = OO / 4;
  ca.src[7] = b2_raw;   ca.dst[7] = b2c;   ca.n4[7] = OO / 4;
  ca.src[8] = br_raw;   ca.dst[8] = brc;   ca.n4[8] = OO / 4;
  ca.src[9] = slw_raw;  ca.dst[9] = slwc;  ca.n4[9] = HH / 4;
  convert_kernel<<<dim3(128, SEG_N), 256, 0, stream>>>(ca);

  // 1) qkv projection (XCD-banded); Q pre-scaled, K row-major, V transposed
  gemm_qkv<<<768, 256, 0, stream>>>(xc, qkvwc, qkvbc, Qb, Kb, Vb, DD);
  // 2) attention (+ query fmask) -> hb (scratch inside d_out)
  attn_kernel<<<BB * HH * (NN / 128), 512, 0, stream>>>(Qb, Kb, Vb, slwc, mask, hb);
  // 3) ffn layer 1 (XCD-banded): relu(h@w1^T + b1), masked rows zeroed
  gemm_ffn<1><<<512, 256, 0, stream>>>(
      hb, w1c, nullptr, nullptr, b1c, nullptr, mask, tb, nullptr, OO, OO);
  // 4) ffn layer 2 + residual (XCD-banded, t-band L2-resident) -> fp32 out
  gemm_ffn<2><<<512, 256, 0, stream>>>(
      tb, w2c, xc, wrc, b2c, brc, mask, nullptr, outf, OO, DD);
}

// Round 3
// 222.245 us; speedup vs baseline: 1.0690x; 1.0001x over previous
//
#include <hip/hip_runtime.h>
#include <hip/hip_bf16.h>

typedef __attribute__((ext_vector_type(8))) short short8;
typedef __attribute__((ext_vector_type(4))) float f32x4;
typedef __attribute__((ext_vector_type(4))) short short4v;

// Problem constants
#define BB 8
#define NN 1024
#define DD 512
#define OO 512
#define HH 8
#define HD 64
#define MM (BB * NN)  // 8192

#define QSC 0.18033688f       // 0.125 * log2(e): folded into Q at projection
#define KSHIFT -11.54156032f  // -8*log2(e): softmax shift, fused into key bias
#define KMASKED -30000.0f     // masked key: exp2 underflows to exactly 0

// Async global->LDS, 16B/lane (m97 recipe). LDS dest = wave-uniform base +
// lane*16 -> unpadded tiles.
__device__ __forceinline__ void gload_lds16(const void* g, void* l) {
  __builtin_amdgcn_global_load_lds(
      (const __attribute__((address_space(1))) void*)g,
      (__attribute__((address_space(3))) void*)l, 16, 0, 0);
}

__device__ __forceinline__ uint2 cvt4(float4 v) {
  union { uint2 u; __hip_bfloat16 h[4]; } t;
  t.h[0] = __float2bfloat16(v.x);
  t.h[1] = __float2bfloat16(v.y);
  t.h[2] = __float2bfloat16(v.z);
  t.h[3] = __float2bfloat16(v.w);
  return t.u;
}

// ---------------------------------------------------------------------------
// Input conversion. PROVEN: float inputs fp32, mask int32 {0,1}, output fp32.
// grid.x = 1024 (was 128: only half the CUs were active).
// ---------------------------------------------------------------------------
#define SEG_N 10
struct ConvArgs {
  const float* src[SEG_N];
  __hip_bfloat16* dst[SEG_N];
  int n4[SEG_N];
};

__global__ void convert_kernel(ConvArgs a) {
  const int t = blockIdx.y;
  const int n4 = a.n4[t];
  const float4* fs = (const float4*)a.src[t];
  uint2* d = (uint2*)a.dst[t];
  for (int i = blockIdx.x * blockDim.x + threadIdx.x; i < n4;
       i += gridDim.x * blockDim.x)
    d[i] = cvt4(fs[i]);
}

// ---------------------------------------------------------------------------
// 128x128-tile GEMM (global_load_lds both sides), qkv epilogue.
// 1D grid of 768, XCD-banded swizzle: XCD k owns rows [1024k, 1024k+1024)
// (x-band 1 MB bf16, L2-resident -> x fetched once per XCD, not 4x).
// Q (pre-scaled QSC), K -> [B,H,N,64]; V -> [B,H,64,N] transposed via LDS.
// ---------------------------------------------------------------------------
__global__ __launch_bounds__(256) void gemm_qkv(
    const __hip_bfloat16* __restrict__ A0, const __hip_bfloat16* __restrict__ B0,
    const __hip_bfloat16* __restrict__ bias0,
    __hip_bfloat16* __restrict__ out0, __hip_bfloat16* __restrict__ out1,
    __hip_bfloat16* __restrict__ out2, int Kd) {
  __shared__ __align__(16) __hip_bfloat16 smem[8192];  // As 128x32 | Bs 128x32
  __hip_bfloat16* As = smem;
  __hip_bfloat16* Bs = smem + 4096;

  const int tid  = threadIdx.x;
  const int wave = tid >> 6;
  const int lane = tid & 63;
  const int fl   = lane & 15;
  const int fk   = (lane >> 4) * 8;
  const int wm   = (wave & 1) * 64;
  const int wn   = (wave >> 1) * 64;
  // XCD-banded swizzle (768 blocks = 64 rowparts x 12 colparts)
  const int bid     = blockIdx.x;
  const int rowpart = 8 * (bid & 7) + ((bid >> 3) & 7);
  const int colpart = bid >> 6;
  const int m0 = rowpart * 128;
  const int n0 = colpart * 128;
  const int glr  = lane >> 2;
  const int glc  = (lane & 3) * 8;

  f32x4 acc[4][4];
#pragma unroll
  for (int i = 0; i < 4; ++i)
#pragma unroll
    for (int j = 0; j < 4; ++j) acc[i][j] = (f32x4){0.f, 0.f, 0.f, 0.f};

  char* lb = (char*)smem;
  for (int k0 = 0; k0 < Kd; k0 += 32) {
    __syncthreads();
    gload_lds16(A0 + (size_t)(m0 + wave * 16 + glr) * Kd + k0 + glc,
                lb + wave * 1024 + lane * 16);
    gload_lds16(A0 + (size_t)(m0 + 64 + wave * 16 + glr) * Kd + k0 + glc,
                lb + (wave + 4) * 1024 + lane * 16);
    gload_lds16(B0 + (size_t)(n0 + wave * 16 + glr) * Kd + k0 + glc,
                lb + 8192 + wave * 1024 + lane * 16);
    gload_lds16(B0 + (size_t)(n0 + 64 + wave * 16 + glr) * Kd + k0 + glc,
                lb + 8192 + (wave + 4) * 1024 + lane * 16);
    __syncthreads();

    short8 af[4], bfr[4];
#pragma unroll
    for (int i = 0; i < 4; ++i)
      af[i] = *(const short8*)&As[(wm + i * 16 + fl) * 32 + fk];
#pragma unroll
    for (int j = 0; j < 4; ++j)
      bfr[j] = *(const short8*)&Bs[(wn + j * 16 + fl) * 32 + fk];
#pragma unroll
    for (int i = 0; i < 4; ++i)
#pragma unroll
      for (int j = 0; j < 4; ++j)
        acc[i][j] = __builtin_amdgcn_mfma_f32_16x16x32_bf16(af[i], bfr[j],
                                                            acc[i][j], 0, 0, 0);
  }

  const int rb = (lane >> 4) * 4;
  const int part = n0 >> 9;  // block-uniform
  if (part < 2) {
    __hip_bfloat16* dst = (part == 0) ? out0 : out1;
    const float scf = (part == 0) ? QSC : 1.0f;
#pragma unroll
    for (int j = 0; j < 4; ++j) {
      const int colb  = n0 + wn + j * 16;
      const int o     = colb & 511;
      const int headq = o >> 6;
      const int d     = (o & 63) + fl;
      const float bi  = __bfloat162float(bias0[colb + fl]);
#pragma unroll
      for (int i = 0; i < 4; ++i) {
#pragma unroll
        for (int r = 0; r < 4; ++r) {
          const int row = m0 + wm + i * 16 + rb + r;
          const int bb  = row >> 10;
          const int nn  = row & 1023;
          dst[((size_t)((bb << 3) + headq) * NN + nn) * HD + d] =
              __float2bfloat16((acc[i][j][r] + bi) * scf);
        }
      }
    }
  } else {
    // V: transpose 64x16 pieces through LDS, coalesced dwordx4 stores
    __syncthreads();  // uniform; smem free for scratch
    __hip_bfloat16* tsc = smem + wave * 1120;  // 16 x 70 per wave
    const int bb  = (m0 + wm) >> 10;
    const int nnb = (m0 + wm) & 1023;
    const int dl  = lane >> 2;
    const int cc  = (lane & 3) * 16;
#pragma unroll
    for (int j = 0; j < 4; ++j) {
      const int colb  = n0 + wn + j * 16;
      const int o     = colb & 511;
      const int headq = o >> 6;
      const int dbase = o & 63;
      const float bi  = __bfloat162float(bias0[colb + fl]);
#pragma unroll
      for (int i = 0; i < 4; ++i) {
#pragma unroll
        for (int r = 0; r < 4; ++r) {
          const int rr = i * 16 + rb + r;
          tsc[fl * 70 + rr] = __float2bfloat16(acc[i][j][r] + bi);
        }
      }
      uint4 r0 = *(const uint4*)&tsc[dl * 70 + cc];
      uint4 r1 = *(const uint4*)&tsc[dl * 70 + cc + 8];
      __hip_bfloat16* vdst =
          out2 + ((size_t)((bb << 3) + headq) * HD + dbase + dl) * NN + nnb;
      *(uint4*)&vdst[cc] = r0;
      *(uint4*)&vdst[cc + 8] = r1;
    }
  }
}

// ---------------------------------------------------------------------------
// Fused FFN: one block per 32-row band (256 blocks = 1/CU, all co-resident).
//   phase 1: h1 = relu(hb_band @ w1^T + b1) * rowmask   -> LDS (bf16)
//   phase 2: acc = h1 @ w2^T + x_band @ wr^T             (K from LDS)
//            out = 0.5*(acc + br + rowmask*b2)           -> fp32 d_out
// Swapped operands (A=weight rows, B=activation rows; attn's S^T trick):
// lane owns 4 consecutive out-cols -> packed b64 h1-writes / float4 stores.
// Weights are L2-resident with zero intra-block reuse -> fragments read
// DIRECTLY global->reg (b128/lane, 2-deep pipeline), no LDS staging, no
// K-loop barriers. 3 barriers total (vs 96 in the split kernels).
// hb lives in d_out (attn scratch), which this kernel overwrites as fp32:
// hb band fully pre-staged to LDS in the first ~1us; outf writes only after
// 48 K-steps (>=6us later); all 256 blocks co-start (single dispatch wave).
// ---------------------------------------------------------------------------
__global__ __launch_bounds__(512) void ffn_fused(
    const __hip_bfloat16* __restrict__ hb, const __hip_bfloat16* __restrict__ xc,
    const __hip_bfloat16* __restrict__ w1, const __hip_bfloat16* __restrict__ w2,
    const __hip_bfloat16* __restrict__ wr,
    const __hip_bfloat16* __restrict__ b1, const __hip_bfloat16* __restrict__ b2,
    const __hip_bfloat16* __restrict__ br,
    const int* __restrict__ mask, float* __restrict__ outf) {
  __shared__ __align__(16) __hip_bfloat16 h1s[32 * 520];  // hb band, then h1
  __shared__ __align__(16) __hip_bfloat16 xs[32 * 520];   // x band
  __shared__ float Mrow[32];

  const int tid  = threadIdx.x;
  const int wv   = tid >> 6;
  const int lane = tid & 63;
  const int fl   = lane & 15;
  const int quad = lane >> 4;
  const int fk   = quad * 8;
  const int m0   = blockIdx.x * 32;

  // ---- pre-stage both activation bands into LDS (coalesced), row mask ----
  {
    const int col = (tid & 63) * 8;
#pragma unroll
    for (int c = 0; c < 4; ++c) {
      const int row = c * 8 + (tid >> 6);
      *(uint4*)&h1s[row * 520 + col] =
          *(const uint4*)&hb[(size_t)(m0 + row) * OO + col];
      *(uint4*)&xs[row * 520 + col] =
          *(const uint4*)&xc[(size_t)(m0 + row) * DD + col];
    }
    if (tid < 32) Mrow[tid] = (mask[m0 + tid] != 0) ? 1.f : 0.f;
  }
  __syncthreads();  // B1

  f32x4 acc[2][4];

  // K-loop: 16 steps of K=32; af[j] = weight rows (wv*64+j*16+fl) direct from
  // global (L2), 2-deep pipelined; bh = activation rows from LDS. 8 MFMA/step.
  auto run_phase = [&](const __hip_bfloat16* __restrict__ W,
                       const __hip_bfloat16* __restrict__ Bsrc) {
    const __hip_bfloat16* wl0 = W + (size_t)(wv * 64 + fl) * 512 + fk;
    short8 a0[4], a1[4];
#pragma unroll
    for (int j = 0; j < 4; ++j) a0[j] = *(const short8*)(wl0 + j * 8192);
    for (int k = 0; k < 16; k += 2) {
#pragma unroll
      for (int j = 0; j < 4; ++j)
        a1[j] = *(const short8*)(wl0 + (k + 1) * 32 + j * 8192);
#pragma unroll
      for (int i = 0; i < 2; ++i) {
        const short8 bh = *(const short8*)&Bsrc[(i * 16 + fl) * 520 + k * 32 + fk];
#pragma unroll
        for (int j = 0; j < 4; ++j)
          acc[i][j] = __builtin_amdgcn_mfma_f32_16x16x32_bf16(a0[j], bh,
                                                              acc[i][j], 0, 0, 0);
      }
      if (k + 2 < 16) {
#pragma unroll
        for (int j = 0; j < 4; ++j)
          a0[j] = *(const short8*)(wl0 + (k + 2) * 32 + j * 8192);
      }
#pragma unroll
      for (int i = 0; i < 2; ++i) {
        const short8 bh =
            *(const short8*)&Bsrc[(i * 16 + fl) * 520 + k * 32 + 32 + fk];
#pragma unroll
        for (int j = 0; j < 4; ++j)
          acc[i][j] = __builtin_amdgcn_mfma_f32_16x16x32_bf16(a1[j], bh,
                                                              acc[i][j], 0, 0, 0);
      }
    }
  };

  const float mr0 = Mrow[fl];
  const float mr1 = Mrow[16 + fl];

  // ---- phase 1: h1 = relu(hb @ w1^T + b1) * rowmask ----
#pragma unroll
  for (int i = 0; i < 2; ++i)
#pragma unroll
    for (int j = 0; j < 4; ++j) acc[i][j] = (f32x4){0.f, 0.f, 0.f, 0.f};
  run_phase(w1, h1s);
  __syncthreads();  // B2: all waves done reading hb band from h1s

#pragma unroll
  for (int j = 0; j < 4; ++j) {
    const int c0 = wv * 64 + j * 16 + quad * 4;
    union { short4v s; __hip_bfloat16 h[4]; } bv;
    bv.s = *(const short4v*)&b1[c0];
#pragma unroll
    for (int i = 0; i < 2; ++i) {
      const float mr = (i == 0) ? mr0 : mr1;
      union { short4v s; __hip_bfloat16 h[4]; } pu;
#pragma unroll
      for (int e = 0; e < 4; ++e) {
        const float v = fmaxf(acc[i][j][e] + __bfloat162float(bv.h[e]), 0.f) * mr;
        pu.h[e] = __float2bfloat16(v);
      }
      *(short4v*)&h1s[(i * 16 + fl) * 520 + c0] = pu.s;
    }
  }
  __syncthreads();  // B3: h1 visible to all waves

  // ---- phase 2: acc = h1 @ w2^T + x @ wr^T ----
#pragma unroll
  for (int i = 0; i < 2; ++i)
#pragma unroll
    for (int j = 0; j < 4; ++j) acc[i][j] = (f32x4){0.f, 0.f, 0.f, 0.f};
  run_phase(w2, h1s);
  run_phase(wr, xs);

#pragma unroll
  for (int j = 0; j < 4; ++j) {
    const int c0 = wv * 64 + j * 16 + quad * 4;
    union { short4v s; __hip_bfloat16 h[4]; } b2v, brv;
    b2v.s = *(const short4v*)&b2[c0];
    brv.s = *(const short4v*)&br[c0];
#pragma unroll
    for (int i = 0; i < 2; ++i) {
      const float mr = (i == 0) ? mr0 : mr1;
      const int row = m0 + i * 16 + fl;
      float4 o;
      o.x = 0.5f * (acc[i][j][0] + __bfloat162float(brv.h[0]) +
                    mr * __bfloat162float(b2v.h[0]));
      o.y = 0.5f * (acc[i][j][1] + __bfloat162float(brv.h[1]) +
                    mr * __bfloat162float(b2v.h[1]));
      o.z = 0.5f * (acc[i][j][2] + __bfloat162float(brv.h[2]) +
                    mr * __bfloat162float(b2v.h[2]));
      o.w = 0.5f * (acc[i][j][3] + __bfloat162float(brv.h[3]) +
                    mr * __bfloat162float(b2v.h[3]));
      *(float4*)&outf[(size_t)row * OO + c0] = o;
    }
  }
}

// ---------------------------------------------------------------------------
// Attention: 128-row Q tile, 512 threads (8 waves x 16 q-rows), KVBLK=64.
// Ps aliased onto Qs (Q register-hoisted); T14 reg prefetch; T5 setprio.
// S^T trick (A=K, B=Q): packed b64 P-writes, float4 mask-bias, scalar lsum.
// Q pre-scaled by 0.125*log2(e); Msf fuses mask + shift (log2 domain).
// blockIdx = qblk*64 + bh (XCD-local K/V).
// ---------------------------------------------------------------------------
__global__ __launch_bounds__(512) void attn_kernel(
    const __hip_bfloat16* __restrict__ Qb, const __hip_bfloat16* __restrict__ Kb,
    const __hip_bfloat16* __restrict__ Vt, const __hip_bfloat16* __restrict__ slw,
    const int* __restrict__ mask, __hip_bfloat16* __restrict__ hb) {
  __shared__ __align__(16) __hip_bfloat16 QPs[128 * 72];  // Q pre-loop, then P
  __shared__ __align__(16) __hip_bfloat16 Ks[64 * 72];
  __shared__ __align__(16) __hip_bfloat16 Vs[64 * 72];
  __shared__ float Msf[NN];

  const int tid  = threadIdx.x;
  const int wave = tid >> 6;
  const int lane = tid & 63;
  const int fl   = lane & 15;
  const int quad = lane >> 4;
  const int fk   = quad * 8;
  const int rb   = quad * 4;
  const int bh   = blockIdx.x & 63;
  const int qblk = blockIdx.x >> 6;
  const int b    = bh >> 3;
  const int head = bh & 7;
  const int q0   = qblk * 128;

  const float slwL2 = __bfloat162float(slw[head]) * 1.44269504f;

  {
    const int srow = tid >> 2;
    const int sc   = (tid & 3) * 16;
    const __hip_bfloat16* qg = Qb + ((size_t)bh * NN + q0) * HD;
    uint4 v0 = *(const uint4*)(qg + srow * HD + sc);
    uint4 v1 = *(const uint4*)(qg + srow * HD + sc + 8);
    *(uint4*)&QPs[srow * 72 + sc] = v0;
    *(uint4*)&QPs[srow * 72 + sc + 8] = v1;
#pragma unroll
    for (int k = 0; k < 2; ++k) {
      const int idx = tid * 2 + k;
      Msf[idx] = (mask[b * NN + idx] != 0) ? KSHIFT : KMASKED;
    }
  }
  __syncthreads();
  // Q register-hoist: QPs is dead after this -> reused as P buffer.
  const short8 qa0 = *(const short8*)&QPs[(wave * 16 + fl) * 72 + fk];
  const short8 qa1 = *(const short8*)&QPs[(wave * 16 + fl) * 72 + fk + 32];

  // staging geometry: K tile 64x64, V^T tile 64x64 -> 1 uint4/thread each
  const int srow2 = tid >> 3;        // 0..63
  const int sc2   = (tid & 7) * 8;   // 0..56

  const __hip_bfloat16* kgb = Kb + (size_t)bh * NN * HD;
  const __hip_bfloat16* vgb = Vt + (size_t)bh * HD * NN;

  // T14 prefetch registers: tile kb=0 (8 VGPRs total)
  uint4 kr = *(const uint4*)(kgb + (size_t)srow2 * HD + sc2);
  uint4 vr = *(const uint4*)(vgb + (size_t)srow2 * NN + sc2);

  float lsum = 0.f;
  f32x4 Oacc[4];
#pragma unroll
  for (int t = 0; t < 4; ++t) Oacc[t] = (f32x4){0.f, 0.f, 0.f, 0.f};

  const int kbdiag = 2 * qblk + (wave >> 2);

  for (int kb = 0; kb < NN / 64; ++kb) {
    const int kbase = kb * 64;
    __syncthreads();  // all waves done reading previous K/V tile
    *(uint4*)&Ks[srow2 * 72 + sc2] = kr;
    *(uint4*)&Vs[srow2 * 72 + sc2] = vr;
    __syncthreads();  // staging visible

    // issue next tile's global loads NOW; consumed at next iteration's
    // staging -> a full tile of compute hides the (L2) load latency.
    if (kb + 1 < NN / 64) {
      const int nk = kbase + 64;
      kr = *(const uint4*)(kgb + (size_t)(nk + srow2) * HD + sc2);
      vr = *(const uint4*)(vgb + (size_t)srow2 * NN + nk + sc2);
    }

    f32x4 sfr[4];
    __builtin_amdgcn_s_setprio(1);
#pragma unroll
    for (int j = 0; j < 4; ++j) {
      const short8 kf0 = *(const short8*)&Ks[(j * 16 + fl) * 72 + fk];
      const short8 kf1 = *(const short8*)&Ks[(j * 16 + fl) * 72 + fk + 32];
      f32x4 z = (f32x4){0.f, 0.f, 0.f, 0.f};
      z = __builtin_amdgcn_mfma_f32_16x16x32_bf16(kf0, qa0, z, 0, 0, 0);
      z = __builtin_amdgcn_mfma_f32_16x16x32_bf16(kf1, qa1, z, 0, 0, 0);
      sfr[j] = z;
    }
    __builtin_amdgcn_s_setprio(0);

    if (kb == kbdiag) {
      if ((fl >> 2) == quad) sfr[wave & 3][fl & 3] += slwL2;
    }

#pragma unroll
    for (int j = 0; j < 4; ++j) {
      const f32x4 mb4 = *(const f32x4*)&Msf[kbase + j * 16 + quad * 4];
      union { short4v s; __hip_bfloat16 h[4]; } pu;
      float ps = 0.f;
#pragma unroll
      for (int e = 0; e < 4; ++e) {
        const float pv = exp2f(sfr[j][e] + mb4[e]);
        ps += pv;
        pu.h[e] = __float2bfloat16(pv);
      }
      lsum += ps;
      *(short4v*)&QPs[(wave * 16 + fl) * 72 + j * 16 + quad * 4] = pu.s;
    }

    const short8 pa0 = *(const short8*)&QPs[(wave * 16 + fl) * 72 + fk];
    const short8 pa1 = *(const short8*)&QPs[(wave * 16 + fl) * 72 + fk + 32];
    __builtin_amdgcn_s_setprio(1);
#pragma unroll
    for (int t = 0; t < 4; ++t) {
      const short8 vf0 = *(const short8*)&Vs[(t * 16 + fl) * 72 + fk];
      const short8 vf1 = *(const short8*)&Vs[(t * 16 + fl) * 72 + fk + 32];
      Oacc[t] = __builtin_amdgcn_mfma_f32_16x16x32_bf16(pa0, vf0, Oacc[t], 0, 0, 0);
      Oacc[t] = __builtin_amdgcn_mfma_f32_16x16x32_bf16(pa1, vf1, Oacc[t], 0, 0, 0);
    }
    __builtin_amdgcn_s_setprio(0);
  }

  float l = lsum;
  l += __shfl_xor(l, 16, 64);
  l += __shfl_xor(l, 32, 64);
  const int qrow_me = q0 + wave * 16 + fl;
  const float qm = (mask[b * NN + qrow_me] != 0) ? 1.f : 0.f;
  const float sf = qm / fmaxf(l, 1e-30f);

  float scl[4];
#pragma unroll
  for (int r = 0; r < 4; ++r) scl[r] = __shfl(sf, rb + r, 64);

#pragma unroll
  for (int t = 0; t < 4; ++t) {
    const int d = t * 16 + fl;
#pragma unroll
    for (int r = 0; r < 4; ++r) {
      const int qrow_g = q0 + wave * 16 + rb + r;
      hb[(size_t)(b * NN + qrow_g) * OO + head * HD + d] =
          __float2bfloat16(Oacc[t][r] * scl[r]);
    }
  }
}

extern "C" void kernel_launch(void* const* d_in, const int* in_sizes, int n_in,
                              void* d_out, int out_size, void* d_ws, size_t ws_size,
                              hipStream_t stream) {
  const float* x_raw    = (const float*)d_in[0];
  const int* mask       = (const int*)d_in[2];
  const float* slw_raw  = (const float*)d_in[3];
  const float* qkvw_raw = (const float*)d_in[4];
  const float* qkvb_raw = (const float*)d_in[5];
  const float* w1_raw   = (const float*)d_in[6];
  const float* b1_raw   = (const float*)d_in[7];
  const float* w2_raw   = (const float*)d_in[8];
  const float* b2_raw   = (const float*)d_in[9];
  const float* wr_raw   = (const float*)d_in[10];
  const float* br_raw   = (const float*)d_in[11];
  float* outf           = (float*)d_out;

  __hip_bfloat16* p = (__hip_bfloat16*)d_ws;
  __hip_bfloat16* xc    = p; p += (size_t)MM * DD;
  __hip_bfloat16* qkvwc = p; p += 3 * OO * DD;
  __hip_bfloat16* w1c   = p; p += OO * OO;
  __hip_bfloat16* w2c   = p; p += OO * OO;
  __hip_bfloat16* wrc   = p; p += OO * DD;
  __hip_bfloat16* qkvbc = p; p += 3 * OO;
  __hip_bfloat16* b1c   = p; p += OO;
  __hip_bfloat16* b2c   = p; p += OO;
  __hip_bfloat16* brc   = p; p += OO;
  __hip_bfloat16* slwc  = p; p += 64;
  const size_t ebuf = (size_t)BB * HH * NN * HD;
  __hip_bfloat16* Qb = p; p += ebuf;
  __hip_bfloat16* Kb = p; p += ebuf;
  __hip_bfloat16* Vb = p; p += ebuf;   // V^T layout [B,H,64,N]
  __hip_bfloat16* hb = (__hip_bfloat16*)d_out;  // attn out scratch in d_out;
                                                // pre-staged to LDS by ffn_fused

  if (ws_size < (size_t)((char*)p - (char*)d_ws)) return;

  ConvArgs ca;
  ca.src[0] = x_raw;    ca.dst[0] = xc;    ca.n4[0] = MM * DD / 4;
  ca.src[1] = qkvw_raw; ca.dst[1] = qkvwc; ca.n4[1] = 3 * OO * DD / 4;
  ca.src[2] = w1_raw;   ca.dst[2] = w1c;   ca.n4[2] = OO * OO / 4;
  ca.src[3] = w2_raw;   ca.dst[3] = w2c;   ca.n4[3] = OO * OO / 4;
  ca.src[4] = wr_raw;   ca.dst[4] = wrc;   ca.n4[4] = OO * DD / 4;
  ca.src[5] = qkvb_raw; ca.dst[5] = qkvbc; ca.n4[5] = 3 * OO / 4;
  ca.src[6] = b1_raw;   ca.dst[6] = b1c;   ca.n4[6] = OO / 4;
  ca.src[7] = b2_raw;   ca.dst[7] = b2c;   ca.n4[7] = OO / 4;
  ca.src[8] = br_raw;   ca.dst[8] = brc;   ca.n4[8] = OO / 4;
  ca.src[9] = slw_raw;  ca.dst[9] = slwc;  ca.n4[9] = HH / 4;
  convert_kernel<<<dim3(1024, SEG_N), 256, 0, stream>>>(ca);

  // 1) qkv projection (XCD-banded); Q pre-scaled, K row-major, V transposed
  gemm_qkv<<<768, 256, 0, stream>>>(xc, qkvwc, qkvbc, Qb, Kb, Vb, DD);
  // 2) attention (+ query fmask) -> hb (scratch inside d_out)
  attn_kernel<<<BB * HH * (NN / 128), 512, 0, stream>>>(Qb, Kb, Vb, slwc, mask, hb);
  // 3+4) fused FFN + residual -> fp32 out (single kernel, 256 blocks)
  ffn_fused<<<256, 512, 0, stream>>>(hb, xc, w1c, w2c, wrc, b1c, b2c, brc,
                                     mask, outf);
}